// Round 2
// baseline (825.866 us; speedup 1.0000x reference)
//
#include <hip/hip_runtime.h>

// Problem constants (B=4, H=W=64, C=256, GROUPS=8)
#define N_TOK 4096          // H*W
#define C_DIM 256
#define BATCH 4
#define M_ROWS (BATCH * N_TOK)   // 16384
#define GN_CNT 131072.0f         // 64*64*32 elements per (b, group)
#define JSPLIT 4                 // attention column chunks (flash-decoding split)

typedef __attribute__((ext_vector_type(4))) float f32x4;
typedef __attribute__((ext_vector_type(8))) short s16x8;      // 8 x bf16 (MFMA A/B frag)
typedef __attribute__((ext_vector_type(4))) unsigned short u16x4;

static __device__ __forceinline__ unsigned short f2bf(float f) {
  unsigned int u = __builtin_bit_cast(unsigned int, f);
  u += 0x7fff + ((u >> 16) & 1);   // RNE
  return (unsigned short)(u >> 16);
}
static __device__ __forceinline__ float bf2f(unsigned short h) {
  unsigned int u = ((unsigned int)h) << 16;
  return __builtin_bit_cast(float, u);
}

// ---------------- weight fp32 -> bf16, transposed: wT[n][k] = w[k][n] ----------
__global__ __launch_bounds__(256) void wtrans(const float* __restrict__ wq,
                                              const float* __restrict__ wk,
                                              const float* __restrict__ wv,
                                              const float* __restrict__ wp,
                                              unsigned short* __restrict__ wT) {
  const float* const srcs[4] = {wq, wk, wv, wp};
  const float* w = srcs[blockIdx.z];
  unsigned short* o = wT + blockIdx.z * 65536;
  __shared__ float t[32][33];
  int k0 = blockIdx.x * 32, n0 = blockIdx.y * 32;
  int tx = threadIdx.x, ty = threadIdx.y;
#pragma unroll
  for (int ky = 0; ky < 32; ky += 8)
    t[ty + ky][tx] = w[(k0 + ty + ky) * C_DIM + n0 + tx];
  __syncthreads();
#pragma unroll
  for (int ky = 0; ky < 32; ky += 8)
    o[(n0 + ty + ky) * C_DIM + k0 + tx] = f2bf(t[tx][ty + ky]);
}

// ---------------- GroupNorm partial stats -> atomics into ws ------------------
__global__ __launch_bounds__(256) void gn_stats(const float* __restrict__ x,
                                                float* __restrict__ partials) {
  int bg = blockIdx.x >> 4, chunk = blockIdx.x & 15;
  int b = bg >> 3, g = bg & 7;
  int tid = threadIdx.x;
  const f32x4* x4 = (const f32x4*)x;
  float s1 = 0.f, s2 = 0.f;
#pragma unroll
  for (int it = 0; it < 8; ++it) {
    int idx = it * 256 + tid;          // 0..2047 float4s in this chunk
    int nl = idx >> 3, cq = idx & 7;   // 256 rows x 8 float4s (=32 ch)
    f32x4 v = x4[(b * N_TOK + chunk * 256 + nl) * 64 + g * 8 + cq];
    s1 += v[0] + v[1] + v[2] + v[3];
    s2 += v[0] * v[0] + v[1] * v[1] + v[2] * v[2] + v[3] * v[3];
  }
  for (int m = 1; m < 64; m <<= 1) {
    s1 += __shfl_xor(s1, m, 64);
    s2 += __shfl_xor(s2, m, 64);
  }
  __shared__ float r1[4], r2[4];
  int wave = tid >> 6, lane = tid & 63;
  if (lane == 0) { r1[wave] = s1; r2[wave] = s2; }
  __syncthreads();
  if (tid == 0) {
    atomicAdd(&partials[bg * 2],     r1[0] + r1[1] + r1[2] + r1[3]);
    atomicAdd(&partials[bg * 2 + 1], r2[0] + r2[1] + r2[2] + r2[3]);
  }
}

// ---------------- GroupNorm normalize -> bf16 xn ------------------------------
__global__ __launch_bounds__(256) void gn_norm(const float* __restrict__ x,
                                               const float* __restrict__ gamma,
                                               const float* __restrict__ beta,
                                               const float* __restrict__ partials,
                                               unsigned short* __restrict__ xn) {
  const f32x4* x4 = (const f32x4*)x;
  const f32x4* g4 = (const f32x4*)gamma;
  const f32x4* b4 = (const f32x4*)beta;
  u16x4* o4 = (u16x4*)xn;
  int t0 = blockIdx.x * 256 + threadIdx.x;
#pragma unroll
  for (int it = 0; it < 4; ++it) {
    int fid = it * 262144 + t0;        // over 1,048,576 float4s
    int row = fid >> 6, c4 = fid & 63;
    int b = row >> 12, g = c4 >> 3;
    int bg = b * 8 + g;
    float inv = 1.f / GN_CNT;
    float mean = partials[bg * 2] * inv;
    float var = partials[bg * 2 + 1] * inv - mean * mean;
    float rstd = rsqrtf(var + 1e-3f);
    f32x4 v = x4[fid], ga = g4[c4], be = b4[c4];
    u16x4 o;
#pragma unroll
    for (int j = 0; j < 4; ++j) o[j] = f2bf((v[j] - mean) * rstd * ga[j] + be[j]);
    o4[fid] = o;
  }
}

// ---------------- QKV GEMM: [16384,256] @ [256,256] + bias -> bf16 ------------
// blockIdx.y selects q/k/v; wave = 16 rows; MFMA 16x16x32 bf16; softmax scale
// (C^-0.5 = 1/16) folded into q.
__global__ __launch_bounds__(256) void qkv_gemm(const unsigned short* __restrict__ xn,
                                                const unsigned short* __restrict__ wT,
                                                const float* __restrict__ bq,
                                                const float* __restrict__ bk,
                                                const float* __restrict__ bv,
                                                unsigned short* __restrict__ qo,
                                                unsigned short* __restrict__ ko,
                                                unsigned short* __restrict__ vo) {
  int tid = threadIdx.x;
  int wave = tid >> 6, lane = tid & 63, g = lane >> 4, c16 = lane & 15;
  int row0 = blockIdx.x * 64 + wave * 16;
  int w = blockIdx.y;
  s16x8 af[8];
#pragma unroll
  for (int s = 0; s < 8; ++s)
    af[s] = *(const s16x8*)(xn + (row0 + c16) * C_DIM + s * 32 + g * 8);
  const float* bias = (w == 0) ? bq : (w == 1) ? bk : bv;
  unsigned short* outp = (w == 0) ? qo : (w == 1) ? ko : vo;
  float scale = (w == 0) ? 0.0625f : 1.f;
  const unsigned short* wt = wT + w * 65536;
  for (int ct = 0; ct < 16; ++ct) {
    float bv0 = bias[ct * 16 + c16];
    f32x4 acc = {bv0, bv0, bv0, bv0};
#pragma unroll
    for (int s = 0; s < 8; ++s) {
      s16x8 bf = *(const s16x8*)(wt + (ct * 16 + c16) * C_DIM + s * 32 + g * 8);
      acc = __builtin_amdgcn_mfma_f32_16x16x32_bf16(af[s], bf, acc, 0, 0, 0);
    }
#pragma unroll
    for (int r = 0; r < 4; ++r)
      outp[(row0 + g * 4 + r) * C_DIM + ct * 16 + c16] = f2bf(acc[r] * scale);
  }
}

// ---------------- V transpose: v[b][n][c] -> vT[b][c][n] ----------------------
__global__ __launch_bounds__(256) void vtrans(const unsigned short* __restrict__ v,
                                              unsigned short* __restrict__ vT) {
  __shared__ unsigned short t[32][33];
  int n0 = blockIdx.x * 32, c0 = blockIdx.y * 32, b = blockIdx.z;
  int tx = threadIdx.x, ty = threadIdx.y;
#pragma unroll
  for (int ky = 0; ky < 32; ky += 8)
    t[ty + ky][tx] = v[(b * N_TOK + n0 + ty + ky) * C_DIM + c0 + tx];
  __syncthreads();
#pragma unroll
  for (int ky = 0; ky < 32; ky += 8)
    vT[(b * C_DIM + c0 + ty + ky) * N_TOK + n0 + tx] = t[tx][ty + ky];
}

// ---------------- Flash attention partial: 16 Q rows/wave, 1024-col chunk -----
// Grid (256, JSPLIT). j-tiles of 64 cols (4 S-tiles per iteration). No block
// barriers in the loop: P roundtrip uses per-wave-private LDS (DS ops are
// in-order per wave). XOR swizzle (16B-unit ^ row&7) -> conflict-free b128.
__global__ __launch_bounds__(256, 3) void attn_part(const unsigned short* __restrict__ q,
                                                    const unsigned short* __restrict__ k,
                                                    const unsigned short* __restrict__ vT,
                                                    unsigned short* __restrict__ Opart,
                                                    float2* __restrict__ ml) {
  int tid = threadIdx.x;
  int wave = tid >> 6, lane = tid & 63, g = lane >> 4, c16 = lane & 15;
  int rowbase = blockIdx.x * 64;     // never spans batches
  int chunk = blockIdx.y;
  int b = rowbase >> 12;
  int qrow0 = rowbase + wave * 16;
  s16x8 qf[8];
#pragma unroll
  for (int s = 0; s < 8; ++s)
    qf[s] = *(const s16x8*)(q + (qrow0 + c16) * C_DIM + s * 32 + g * 8);
  const unsigned short* kb = k + b * N_TOK * C_DIM;
  const unsigned short* vb = vT + b * C_DIM * N_TOK;
  __shared__ __align__(16) unsigned short pb[4][1024];  // per-wave 16x64 P tile
  unsigned short* myp = pb[wave];
  int h = c16 & 7;
  f32x4 Oa[16];
#pragma unroll
  for (int ct = 0; ct < 16; ++ct) Oa[ct] = (f32x4){0.f, 0.f, 0.f, 0.f};
  float ms[4] = {-1e30f, -1e30f, -1e30f, -1e30f};
  float ls[4] = {0.f, 0.f, 0.f, 0.f};

  for (int jt = 0; jt < 16; ++jt) {
    int jbase = chunk * 1024 + jt * 64;
    f32x4 sc[4];
#pragma unroll
    for (int t = 0; t < 4; ++t) sc[t] = (f32x4){0.f, 0.f, 0.f, 0.f};
#pragma unroll
    for (int kk = 0; kk < 8; ++kk) {
#pragma unroll
      for (int t = 0; t < 4; ++t) {
        s16x8 kf = *(const s16x8*)(kb + (jbase + t * 16 + c16) * C_DIM + kk * 32 + g * 8);
        sc[t] = __builtin_amdgcn_mfma_f32_16x16x32_bf16(qf[kk], kf, sc[t], 0, 0, 0);
      }
    }
    // online softmax; S row = g*4+r held by the 16 lanes of group g
    float p[4][4], alpha[4];
    bool need = false;
#pragma unroll
    for (int r = 0; r < 4; ++r) {
      float mx = fmaxf(fmaxf(sc[0][r], sc[1][r]), fmaxf(sc[2][r], sc[3][r]));
      mx = fmaxf(mx, __shfl_xor(mx, 1)); mx = fmaxf(mx, __shfl_xor(mx, 2));
      mx = fmaxf(mx, __shfl_xor(mx, 4)); mx = fmaxf(mx, __shfl_xor(mx, 8));
      float mn = fmaxf(ms[r], mx);
      alpha[r] = __expf(ms[r] - mn);
      ms[r] = mn;
      float rs = 0.f;
#pragma unroll
      for (int t = 0; t < 4; ++t) { p[t][r] = __expf(sc[t][r] - mn); rs += p[t][r]; }
      rs += __shfl_xor(rs, 1); rs += __shfl_xor(rs, 2);
      rs += __shfl_xor(rs, 4); rs += __shfl_xor(rs, 8);
      ls[r] = ls[r] * alpha[r] + rs;
      need |= (alpha[r] < 1.f);
    }
    if (__any(need)) {
#pragma unroll
      for (int ct = 0; ct < 16; ++ct)
#pragma unroll
        for (int r = 0; r < 4; ++r) Oa[ct][r] *= alpha[r];
    }
    // P: C-layout -> LDS (XOR-swizzled) -> A-layout, per-wave private
#pragma unroll
    for (int r = 0; r < 4; ++r) {
      int row = g * 4 + r, rh = row & 7;
#pragma unroll
      for (int t = 0; t < 4; ++t) {
        int col = t * 16 + c16;
        myp[row * 64 + (((col >> 3) ^ rh) << 3) + (col & 7)] = f2bf(p[t][r]);
      }
    }
    s16x8 pf0 = *(const s16x8*)(myp + c16 * 64 + ((g ^ h) << 3));
    s16x8 pf1 = *(const s16x8*)(myp + c16 * 64 + (((4 + g) ^ h) << 3));
#pragma unroll
    for (int ct = 0; ct < 16; ++ct) {
      s16x8 vf0 = *(const s16x8*)(vb + (ct * 16 + c16) * N_TOK + jbase + g * 8);
      s16x8 vf1 = *(const s16x8*)(vb + (ct * 16 + c16) * N_TOK + jbase + 32 + g * 8);
      Oa[ct] = __builtin_amdgcn_mfma_f32_16x16x32_bf16(pf0, vf0, Oa[ct], 0, 0, 0);
      Oa[ct] = __builtin_amdgcn_mfma_f32_16x16x32_bf16(pf1, vf1, Oa[ct], 0, 0, 0);
    }
  }
  // write unnormalized partial O (bf16) + (m,l)
  unsigned short* op = Opart + (size_t)chunk * M_ROWS * C_DIM;
#pragma unroll
  for (int ct = 0; ct < 16; ++ct)
#pragma unroll
    for (int r = 0; r < 4; ++r)
      op[(qrow0 + g * 4 + r) * C_DIM + ct * 16 + c16] = f2bf(Oa[ct][r]);
  if (c16 == 0) {
#pragma unroll
    for (int r = 0; r < 4; ++r)
      ml[chunk * M_ROWS + qrow0 + g * 4 + r] = make_float2(ms[r], ls[r]);
  }
}

// ---------------- Combine JSPLIT partials -> bf16 attention output ------------
__global__ __launch_bounds__(256) void attn_combine(const unsigned short* __restrict__ Opart,
                                                    const float2* __restrict__ ml,
                                                    unsigned short* __restrict__ ab) {
  int row = blockIdx.x * 4 + (threadIdx.x >> 6);
  int lane = threadIdx.x & 63;
  float2 m[JSPLIT];
  float M = -1e30f;
#pragma unroll
  for (int i = 0; i < JSPLIT; ++i) { m[i] = ml[i * M_ROWS + row]; M = fmaxf(M, m[i].x); }
  float w[JSPLIT], L = 0.f;
#pragma unroll
  for (int i = 0; i < JSPLIT; ++i) { w[i] = __expf(m[i].x - M); L += m[i].y * w[i]; }
  float invL = 1.f / L;
  float acc[4] = {0.f, 0.f, 0.f, 0.f};
#pragma unroll
  for (int i = 0; i < JSPLIT; ++i) {
    u16x4 o = *(const u16x4*)(Opart + ((size_t)i * M_ROWS + row) * C_DIM + lane * 4);
#pragma unroll
    for (int j = 0; j < 4; ++j) acc[j] += bf2f(o[j]) * w[i];
  }
  u16x4 o;
#pragma unroll
  for (int j = 0; j < 4; ++j) o[j] = f2bf(acc[j] * invL);
  *(u16x4*)(ab + (size_t)row * C_DIM + lane * 4) = o;
}

// ---------------- Output projection + bias + residual -> fp32 out -------------
// blockIdx.y splits the 16 ct column-tiles into two halves (occupancy).
__global__ __launch_bounds__(256) void proj_gemm(const unsigned short* __restrict__ a,
                                                 const unsigned short* __restrict__ wt,
                                                 const float* __restrict__ bp,
                                                 const float* __restrict__ x,
                                                 float* __restrict__ out) {
  int tid = threadIdx.x;
  int wave = tid >> 6, lane = tid & 63, g = lane >> 4, c16 = lane & 15;
  int row0 = blockIdx.x * 64 + wave * 16;
  int ct0 = blockIdx.y * 8;
  s16x8 af[8];
#pragma unroll
  for (int s = 0; s < 8; ++s)
    af[s] = *(const s16x8*)(a + (row0 + c16) * C_DIM + s * 32 + g * 8);
  for (int ct = ct0; ct < ct0 + 8; ++ct) {
    float bias = bp[ct * 16 + c16];
    f32x4 acc = {bias, bias, bias, bias};
#pragma unroll
    for (int s = 0; s < 8; ++s) {
      s16x8 bf = *(const s16x8*)(wt + (ct * 16 + c16) * C_DIM + s * 32 + g * 8);
      acc = __builtin_amdgcn_mfma_f32_16x16x32_bf16(af[s], bf, acc, 0, 0, 0);
    }
#pragma unroll
    for (int r = 0; r < 4; ++r) {
      int idx = (row0 + g * 4 + r) * C_DIM + ct * 16 + c16;
      out[idx] = acc[r] + x[idx];
    }
  }
}

extern "C" void kernel_launch(void* const* d_in, const int* in_sizes, int n_in,
                              void* d_out, int out_size, void* d_ws, size_t ws_size,
                              hipStream_t stream) {
  const float* x     = (const float*)d_in[0];
  const float* gamma = (const float*)d_in[1];
  const float* beta  = (const float*)d_in[2];
  const float* wq    = (const float*)d_in[3];
  const float* bq    = (const float*)d_in[4];
  const float* wk    = (const float*)d_in[5];
  const float* bk    = (const float*)d_in[6];
  const float* wv    = (const float*)d_in[7];
  const float* bv    = (const float*)d_in[8];
  const float* wp    = (const float*)d_in[9];
  const float* bp    = (const float*)d_in[10];
  float* out = (float*)d_out;

  char* ws = (char*)d_ws;
  float* partials      = (float*)ws;                          // 64 floats
  unsigned short* wT   = (unsigned short*)(ws + 1024);        // 4 x 256x256 bf16
  unsigned short* xnb  = wT + 4 * 65536;                      // xn bf16 [16384,256]
  unsigned short* qb   = xnb + (size_t)M_ROWS * C_DIM;
  unsigned short* kbuf = qb + (size_t)M_ROWS * C_DIM;
  unsigned short* vb   = kbuf + (size_t)M_ROWS * C_DIM;
  unsigned short* vTb  = vb + (size_t)M_ROWS * C_DIM;
  unsigned short* Opart = vTb + (size_t)M_ROWS * C_DIM;       // JSPLIT x [16384,256] bf16
  float2* ml           = (float2*)(Opart + (size_t)JSPLIT * M_ROWS * C_DIM);
  unsigned short* ab   = xnb;   // reuse xn buffer for attention output (xn dead after qkv)

  hipMemsetAsync(partials, 0, 64 * sizeof(float), stream);
  wtrans<<<dim3(8, 8, 4), dim3(32, 8), 0, stream>>>(wq, wk, wv, wp, wT);
  gn_stats<<<512, 256, 0, stream>>>(x, partials);
  gn_norm<<<1024, 256, 0, stream>>>(x, gamma, beta, partials, xnb);
  qkv_gemm<<<dim3(256, 3), 256, 0, stream>>>(xnb, wT, bq, bk, bv, qb, kbuf, vb);
  vtrans<<<dim3(128, 8, 4), dim3(32, 8), 0, stream>>>(vb, vTb);
  attn_part<<<dim3(256, JSPLIT), 256, 0, stream>>>(qb, kbuf, vTb, Opart, ml);
  attn_combine<<<4096, 256, 0, stream>>>(Opart, ml, ab);
  proj_gemm<<<dim3(256, 2), 256, 0, stream>>>(ab, wT + 3 * 65536, bp, x, out);
}

// Round 3
// 294.188 us; speedup vs baseline: 2.8073x; 2.8073x over previous
//
#include <hip/hip_runtime.h>

// Problem constants (B=4, H=W=64, C=256, GROUPS=8)
#define N_TOK 4096          // H*W
#define C_DIM 256
#define BATCH 4
#define M_ROWS (BATCH * N_TOK)   // 16384
#define GN_CNT 131072.0f         // 64*64*32 elements per (b, group)
#define JSPLIT 2                 // attention column chunks (flash-decoding split)

typedef __attribute__((ext_vector_type(4))) float f32x4;
typedef __attribute__((ext_vector_type(8))) short s16x8;      // 8 x bf16 (MFMA A/B frag)
typedef __attribute__((ext_vector_type(4))) unsigned short u16x4;

static __device__ __forceinline__ unsigned short f2bf(float f) {
  unsigned int u = __builtin_bit_cast(unsigned int, f);
  u += 0x7fff + ((u >> 16) & 1);   // RNE
  return (unsigned short)(u >> 16);
}
static __device__ __forceinline__ float bf2f(unsigned short h) {
  unsigned int u = ((unsigned int)h) << 16;
  return __builtin_bit_cast(float, u);
}

// async global->LDS DMA, 16 B per lane. LDS dest must be wave-uniform base +
// lane*16 (hardware constraint); we always call with dst = buf + u*8 elems
// where u = ii*256 + tid, which satisfies it.
static __device__ __forceinline__ void gload_lds16(const void* g, void* l) {
  __builtin_amdgcn_global_load_lds(
      (__attribute__((address_space(1))) void*)(unsigned long long)(const char*)g,
      (__attribute__((address_space(3))) void*)l, 16, 0, 0);
}

// ---------------- weight fp32 -> bf16, transposed: wT[n][k] = w[k][n] ----------
__global__ __launch_bounds__(256) void wtrans(const float* __restrict__ wq,
                                              const float* __restrict__ wk,
                                              const float* __restrict__ wv,
                                              const float* __restrict__ wp,
                                              unsigned short* __restrict__ wT) {
  const float* const srcs[4] = {wq, wk, wv, wp};
  const float* w = srcs[blockIdx.z];
  unsigned short* o = wT + blockIdx.z * 65536;
  __shared__ float t[32][33];
  int k0 = blockIdx.x * 32, n0 = blockIdx.y * 32;
  int tx = threadIdx.x, ty = threadIdx.y;
#pragma unroll
  for (int ky = 0; ky < 32; ky += 8)
    t[ty + ky][tx] = w[(k0 + ty + ky) * C_DIM + n0 + tx];
  __syncthreads();
#pragma unroll
  for (int ky = 0; ky < 32; ky += 8)
    o[(n0 + ty + ky) * C_DIM + k0 + tx] = f2bf(t[tx][ty + ky]);
}

// ---------------- GroupNorm partial stats -> atomics into ws ------------------
__global__ __launch_bounds__(256) void gn_stats(const float* __restrict__ x,
                                                float* __restrict__ partials) {
  int bg = blockIdx.x >> 4, chunk = blockIdx.x & 15;
  int b = bg >> 3, g = bg & 7;
  int tid = threadIdx.x;
  const f32x4* x4 = (const f32x4*)x;
  float s1 = 0.f, s2 = 0.f;
#pragma unroll
  for (int it = 0; it < 8; ++it) {
    int idx = it * 256 + tid;
    int nl = idx >> 3, cq = idx & 7;
    f32x4 v = x4[(b * N_TOK + chunk * 256 + nl) * 64 + g * 8 + cq];
    s1 += v[0] + v[1] + v[2] + v[3];
    s2 += v[0] * v[0] + v[1] * v[1] + v[2] * v[2] + v[3] * v[3];
  }
  for (int m = 1; m < 64; m <<= 1) {
    s1 += __shfl_xor(s1, m, 64);
    s2 += __shfl_xor(s2, m, 64);
  }
  __shared__ float r1[4], r2[4];
  int wave = tid >> 6, lane = tid & 63;
  if (lane == 0) { r1[wave] = s1; r2[wave] = s2; }
  __syncthreads();
  if (tid == 0) {
    atomicAdd(&partials[bg * 2],     r1[0] + r1[1] + r1[2] + r1[3]);
    atomicAdd(&partials[bg * 2 + 1], r2[0] + r2[1] + r2[2] + r2[3]);
  }
}

// ---------------- GroupNorm normalize -> bf16 xn ------------------------------
__global__ __launch_bounds__(256) void gn_norm(const float* __restrict__ x,
                                               const float* __restrict__ gamma,
                                               const float* __restrict__ beta,
                                               const float* __restrict__ partials,
                                               unsigned short* __restrict__ xn) {
  const f32x4* x4 = (const f32x4*)x;
  const f32x4* g4 = (const f32x4*)gamma;
  const f32x4* b4 = (const f32x4*)beta;
  u16x4* o4 = (u16x4*)xn;
  int t0 = blockIdx.x * 256 + threadIdx.x;
#pragma unroll
  for (int it = 0; it < 4; ++it) {
    int fid = it * 262144 + t0;
    int row = fid >> 6, c4 = fid & 63;
    int b = row >> 12, g = c4 >> 3;
    int bg = b * 8 + g;
    float inv = 1.f / GN_CNT;
    float mean = partials[bg * 2] * inv;
    float var = partials[bg * 2 + 1] * inv - mean * mean;
    float rstd = rsqrtf(var + 1e-3f);
    f32x4 v = x4[fid], ga = g4[c4], be = b4[c4];
    u16x4 o;
#pragma unroll
    for (int j = 0; j < 4; ++j) o[j] = f2bf((v[j] - mean) * rstd * ga[j] + be[j]);
    o4[fid] = o;
  }
}

// ---------------- QKV GEMM: [16384,256] @ [256,256] + bias -> bf16 ------------
__global__ __launch_bounds__(256) void qkv_gemm(const unsigned short* __restrict__ xn,
                                                const unsigned short* __restrict__ wT,
                                                const float* __restrict__ bq,
                                                const float* __restrict__ bk,
                                                const float* __restrict__ bv,
                                                unsigned short* __restrict__ qo,
                                                unsigned short* __restrict__ ko,
                                                unsigned short* __restrict__ vo) {
  int tid = threadIdx.x;
  int wave = tid >> 6, lane = tid & 63, g = lane >> 4, c16 = lane & 15;
  int row0 = blockIdx.x * 64 + wave * 16;
  int w = blockIdx.y;
  s16x8 af[8];
#pragma unroll
  for (int s = 0; s < 8; ++s)
    af[s] = *(const s16x8*)(xn + (row0 + c16) * C_DIM + s * 32 + g * 8);
  const float* bias = (w == 0) ? bq : (w == 1) ? bk : bv;
  unsigned short* outp = (w == 0) ? qo : (w == 1) ? ko : vo;
  float scale = (w == 0) ? 0.0625f : 1.f;   // q absorbs softmax scale C^-0.5
  const unsigned short* wt = wT + w * 65536;
  for (int ct = 0; ct < 16; ++ct) {
    float bv0 = bias[ct * 16 + c16];
    f32x4 acc = {bv0, bv0, bv0, bv0};
#pragma unroll
    for (int s = 0; s < 8; ++s) {
      s16x8 bf = *(const s16x8*)(wt + (ct * 16 + c16) * C_DIM + s * 32 + g * 8);
      acc = __builtin_amdgcn_mfma_f32_16x16x32_bf16(af[s], bf, acc, 0, 0, 0);
    }
#pragma unroll
    for (int r = 0; r < 4; ++r)
      outp[(row0 + g * 4 + r) * C_DIM + ct * 16 + c16] = f2bf(acc[r] * scale);
  }
}

// ---------------- V transpose: v[b][n][c] -> vT[b][c][n] ----------------------
__global__ __launch_bounds__(256) void vtrans(const unsigned short* __restrict__ v,
                                              unsigned short* __restrict__ vT) {
  __shared__ unsigned short t[32][33];
  int n0 = blockIdx.x * 32, c0 = blockIdx.y * 32, b = blockIdx.z;
  int tx = threadIdx.x, ty = threadIdx.y;
#pragma unroll
  for (int ky = 0; ky < 32; ky += 8)
    t[ty + ky][tx] = v[(b * N_TOK + n0 + ty + ky) * C_DIM + c0 + tx];
  __syncthreads();
#pragma unroll
  for (int ky = 0; ky < 32; ky += 8)
    vT[(b * C_DIM + c0 + ty + ky) * N_TOK + n0 + tx] = t[tx][ty + ky];
}

// ---------------- Flash attention with LDS tile staging ----------------------
// Block: 4 waves x 16 Q rows = 64 Q rows; j-chunk of 2048 cols (JSPLIT=2) in
// 32 j-tiles of 64 cols. Per j-tile: K(64x256,32KB) + V(256x64,32KB) staged
// into LDS via global_load_lds w=16, XOR-swizzled at the SOURCE address so the
// linear DMA yields conflict-free ds_read_b128 (2-way only). P roundtrip is
// overlaid into the dead K region (barrier-guarded). 64 KB LDS -> 2 blocks/CU.
// blockIdx swizzle pins each batch to one XCD pair for L2-resident K/V.
__global__ __launch_bounds__(256, 2) void attn_part(const unsigned short* __restrict__ q,
                                                    const unsigned short* __restrict__ k,
                                                    const unsigned short* __restrict__ vT,
                                                    unsigned short* __restrict__ Opart,
                                                    float2* __restrict__ ml) {
  int tid = threadIdx.x;
  int wave = tid >> 6, lane = tid & 63, g = lane >> 4, c16 = lane & 15;
  // batch -> XCD-pair swizzle (assumes XCD = blockIdx % 8; perf heuristic only)
  int i = blockIdx.x;                 // 0..511
  int batch = (i >> 1) & 3;
  int slot = ((i >> 3) << 1) | (i & 1);   // 0..127
  int qb = slot & 63, chunk = slot >> 6;
  int qrow0 = batch * N_TOK + qb * 64 + wave * 16;
  const unsigned short* kb = k + (size_t)batch * N_TOK * C_DIM;
  const unsigned short* vb = vT + (size_t)batch * C_DIM * N_TOK;

  __shared__ __align__(16) unsigned short Kt[16384];   // 64 rows x 256 ch
  __shared__ __align__(16) unsigned short Vt[16384];   // 256 ch x 64 cols
  unsigned short* myp = Kt + wave * 1024;              // P overlay, wave-private 2KB

  s16x8 qf[8];
#pragma unroll
  for (int s = 0; s < 8; ++s)
    qf[s] = *(const s16x8*)(q + (qrow0 + c16) * C_DIM + s * 32 + g * 8);

  f32x4 Oa[16];
#pragma unroll
  for (int ct = 0; ct < 16; ++ct) Oa[ct] = (f32x4){0.f, 0.f, 0.f, 0.f};
  float ms[4] = {-1e30f, -1e30f, -1e30f, -1e30f};
  float ls[4] = {0.f, 0.f, 0.f, 0.f};
  int h7 = c16 & 7;

  for (int jt = 0; jt < 32; ++jt) {
    int jbase = chunk * 2048 + jt * 64;
    // ---- stage K tile: 2048 16B-units, source-swizzled ----
#pragma unroll
    for (int ii = 0; ii < 8; ++ii) {
      int u = ii * 256 + tid;
      int row = u >> 5, un = u & 31;
      gload_lds16(kb + (size_t)(jbase + row) * C_DIM + ((un ^ (row & 7)) * 8), Kt + u * 8);
    }
    // ---- stage V tile: 2048 16B-units (rows of vT, 128B each) ----
#pragma unroll
    for (int ii = 0; ii < 8; ++ii) {
      int u = ii * 256 + tid;
      int row = u >> 3, un = u & 7;
      gload_lds16(vb + (size_t)row * N_TOK + jbase + ((un ^ (row & 7)) * 8), Vt + u * 8);
    }
    __syncthreads();   // vmcnt drained by compiler -> tiles resident

    // ---- QK^T: S[16x64] = 4 tiles ----
    f32x4 sc[4];
#pragma unroll
    for (int t = 0; t < 4; ++t) sc[t] = (f32x4){0.f, 0.f, 0.f, 0.f};
#pragma unroll
    for (int kk = 0; kk < 8; ++kk) {
#pragma unroll
      for (int t = 0; t < 4; ++t) {
        s16x8 kf = *(const s16x8*)(Kt + (t * 16 + c16) * C_DIM + (((kk * 4 + g) ^ h7) * 8));
        sc[t] = __builtin_amdgcn_mfma_f32_16x16x32_bf16(qf[kk], kf, sc[t], 0, 0, 0);
      }
    }
    // ---- online softmax (rows g*4+r live in the 16 lanes of group g) ----
    float p[4][4], alpha[4];
    bool need = false;
#pragma unroll
    for (int r = 0; r < 4; ++r) {
      float mx = fmaxf(fmaxf(sc[0][r], sc[1][r]), fmaxf(sc[2][r], sc[3][r]));
      mx = fmaxf(mx, __shfl_xor(mx, 1)); mx = fmaxf(mx, __shfl_xor(mx, 2));
      mx = fmaxf(mx, __shfl_xor(mx, 4)); mx = fmaxf(mx, __shfl_xor(mx, 8));
      float mn = fmaxf(ms[r], mx);
      alpha[r] = __expf(ms[r] - mn);
      ms[r] = mn;
      float rs = 0.f;
#pragma unroll
      for (int t = 0; t < 4; ++t) { p[t][r] = __expf(sc[t][r] - mn); rs += p[t][r]; }
      rs += __shfl_xor(rs, 1); rs += __shfl_xor(rs, 2);
      rs += __shfl_xor(rs, 4); rs += __shfl_xor(rs, 8);
      ls[r] = ls[r] * alpha[r] + rs;
      need |= (alpha[r] < 1.f);
    }
    __syncthreads();   // all waves done reading Kt -> safe to overlay P

    // ---- P: C-layout -> LDS (swizzled) -> A-layout, wave-private ----
#pragma unroll
    for (int r = 0; r < 4; ++r) {
      int row = g * 4 + r, rh = row & 7;
#pragma unroll
      for (int t = 0; t < 4; ++t)
        myp[row * 64 + (((t * 2 + (c16 >> 3)) ^ rh) * 8) + (c16 & 7)] = f2bf(p[t][r]);
    }
    s16x8 pf0 = *(const s16x8*)(myp + c16 * 64 + ((g ^ h7) * 8));
    s16x8 pf1 = *(const s16x8*)(myp + c16 * 64 + (((4 + g) ^ h7) * 8));
    if (__any(need)) {
#pragma unroll
      for (int ct = 0; ct < 16; ++ct)
#pragma unroll
        for (int r = 0; r < 4; ++r) Oa[ct][r] *= alpha[r];
    }
    // ---- PV: O += P @ V ----
#pragma unroll
    for (int ct = 0; ct < 16; ++ct) {
      int row = ct * 16 + c16;
      s16x8 vf0 = *(const s16x8*)(Vt + row * 64 + ((g ^ h7) * 8));
      s16x8 vf1 = *(const s16x8*)(Vt + row * 64 + (((4 + g) ^ h7) * 8));
      Oa[ct] = __builtin_amdgcn_mfma_f32_16x16x32_bf16(pf0, vf0, Oa[ct], 0, 0, 0);
      Oa[ct] = __builtin_amdgcn_mfma_f32_16x16x32_bf16(pf1, vf1, Oa[ct], 0, 0, 0);
    }
    __syncthreads();   // V + P(K-region) reads done -> safe to restage
  }
  // write unnormalized partial O (bf16) + (m,l)
  unsigned short* op = Opart + (size_t)chunk * M_ROWS * C_DIM;
#pragma unroll
  for (int ct = 0; ct < 16; ++ct)
#pragma unroll
    for (int r = 0; r < 4; ++r)
      op[(qrow0 + g * 4 + r) * C_DIM + ct * 16 + c16] = f2bf(Oa[ct][r]);
  if (c16 == 0) {
#pragma unroll
    for (int r = 0; r < 4; ++r)
      ml[chunk * M_ROWS + qrow0 + g * 4 + r] = make_float2(ms[r], ls[r]);
  }
}

// ---------------- Combine JSPLIT partials -> bf16 attention output ------------
__global__ __launch_bounds__(256) void attn_combine(const unsigned short* __restrict__ Opart,
                                                    const float2* __restrict__ ml,
                                                    unsigned short* __restrict__ ab) {
  int row = blockIdx.x * 4 + (threadIdx.x >> 6);
  int lane = threadIdx.x & 63;
  float2 m[JSPLIT];
  float M = -1e30f;
#pragma unroll
  for (int i = 0; i < JSPLIT; ++i) { m[i] = ml[i * M_ROWS + row]; M = fmaxf(M, m[i].x); }
  float w[JSPLIT], L = 0.f;
#pragma unroll
  for (int i = 0; i < JSPLIT; ++i) { w[i] = __expf(m[i].x - M); L += m[i].y * w[i]; }
  float invL = 1.f / L;
  float acc[4] = {0.f, 0.f, 0.f, 0.f};
#pragma unroll
  for (int i = 0; i < JSPLIT; ++i) {
    u16x4 o = *(const u16x4*)(Opart + ((size_t)i * M_ROWS + row) * C_DIM + lane * 4);
#pragma unroll
    for (int j = 0; j < 4; ++j) acc[j] += bf2f(o[j]) * w[i];
  }
  u16x4 o;
#pragma unroll
  for (int j = 0; j < 4; ++j) o[j] = f2bf(acc[j] * invL);
  *(u16x4*)(ab + (size_t)row * C_DIM + lane * 4) = o;
}

// ---------------- Output projection + bias + residual -> fp32 out -------------
__global__ __launch_bounds__(256) void proj_gemm(const unsigned short* __restrict__ a,
                                                 const unsigned short* __restrict__ wt,
                                                 const float* __restrict__ bp,
                                                 const float* __restrict__ x,
                                                 float* __restrict__ out) {
  int tid = threadIdx.x;
  int wave = tid >> 6, lane = tid & 63, g = lane >> 4, c16 = lane & 15;
  int row0 = blockIdx.x * 64 + wave * 16;
  int ct0 = blockIdx.y * 8;
  s16x8 af[8];
#pragma unroll
  for (int s = 0; s < 8; ++s)
    af[s] = *(const s16x8*)(a + (row0 + c16) * C_DIM + s * 32 + g * 8);
  for (int ct = ct0; ct < ct0 + 8; ++ct) {
    float bias = bp[ct * 16 + c16];
    f32x4 acc = {bias, bias, bias, bias};
#pragma unroll
    for (int s = 0; s < 8; ++s) {
      s16x8 bf = *(const s16x8*)(wt + (ct * 16 + c16) * C_DIM + s * 32 + g * 8);
      acc = __builtin_amdgcn_mfma_f32_16x16x32_bf16(af[s], bf, acc, 0, 0, 0);
    }
#pragma unroll
    for (int r = 0; r < 4; ++r) {
      int idx = (row0 + g * 4 + r) * C_DIM + ct * 16 + c16;
      out[idx] = acc[r] + x[idx];
    }
  }
}

extern "C" void kernel_launch(void* const* d_in, const int* in_sizes, int n_in,
                              void* d_out, int out_size, void* d_ws, size_t ws_size,
                              hipStream_t stream) {
  const float* x     = (const float*)d_in[0];
  const float* gamma = (const float*)d_in[1];
  const float* beta  = (const float*)d_in[2];
  const float* wq    = (const float*)d_in[3];
  const float* bq    = (const float*)d_in[4];
  const float* wk    = (const float*)d_in[5];
  const float* bk    = (const float*)d_in[6];
  const float* wv    = (const float*)d_in[7];
  const float* bv    = (const float*)d_in[8];
  const float* wp    = (const float*)d_in[9];
  const float* bp    = (const float*)d_in[10];
  float* out = (float*)d_out;

  char* ws = (char*)d_ws;
  float* partials      = (float*)ws;                          // 64 floats
  unsigned short* wT   = (unsigned short*)(ws + 1024);        // 4 x 256x256 bf16
  unsigned short* xnb  = wT + 4 * 65536;                      // xn bf16 [16384,256]
  unsigned short* qb   = xnb + (size_t)M_ROWS * C_DIM;
  unsigned short* kbuf = qb + (size_t)M_ROWS * C_DIM;
  unsigned short* vb   = kbuf + (size_t)M_ROWS * C_DIM;
  unsigned short* vTb  = vb + (size_t)M_ROWS * C_DIM;
  unsigned short* Opart = vTb + (size_t)M_ROWS * C_DIM;       // JSPLIT x [16384,256] bf16
  float2* ml           = (float2*)(Opart + (size_t)JSPLIT * M_ROWS * C_DIM);
  unsigned short* ab   = xnb;   // reuse xn buffer for attention output (xn dead after qkv)

  hipMemsetAsync(partials, 0, 64 * sizeof(float), stream);
  wtrans<<<dim3(8, 8, 4), dim3(32, 8), 0, stream>>>(wq, wk, wv, wp, wT);
  gn_stats<<<512, 256, 0, stream>>>(x, partials);
  gn_norm<<<1024, 256, 0, stream>>>(x, gamma, beta, partials, xnb);
  qkv_gemm<<<dim3(256, 3), 256, 0, stream>>>(xnb, wT, bq, bk, bv, qb, kbuf, vb);
  vtrans<<<dim3(128, 8, 4), dim3(32, 8), 0, stream>>>(vb, vTb);
  attn_part<<<512, 256, 0, stream>>>(qb, kbuf, vTb, Opart, ml);
  attn_combine<<<4096, 256, 0, stream>>>(Opart, ml, ab);
  proj_gemm<<<dim3(256, 2), 256, 0, stream>>>(ab, wT + 3 * 65536, bp, x, out);
}